// Round 2
// baseline (2967.784 us; speedup 1.0000x reference)
//
#include <hip/hip_runtime.h>

#define CCH 32
#define NPIX 65536
#define NVOX (128 * 128 * 64)   // 2^20
#define NBINS 4096
#define VPB 256                 // voxels per bin  (v & 255)
#define CAP 5120                // slots per bin; Poisson mean 3906, sigma 62 -> 19 sigma headroom
#define EVB 32768               // events per block in the binning pass

typedef unsigned int u32;

// feats[c][i] (C x N_PIX) -> feats_t[i][c] (N_PIX x C), 8 MB
__global__ __launch_bounds__(256) void transpose_feats_k(
    const float* __restrict__ feats, float* __restrict__ feats_t)
{
    int gid = blockIdx.x * 256 + threadIdx.x;
    int i = gid >> 5;
    int c = gid & 31;
    feats_t[gid] = feats[(size_t)c * NPIX + i];
}

// Counting-sort events into 4096 voxel bins. Per-block LDS histogram ->
// one chunk-reserving global atomic per nonzero bin -> packed scatter.
__global__ __launch_bounds__(256) void scatter_bin_k(
    const int* __restrict__ vox_s, const int* __restrict__ vox_d,
    const int* __restrict__ idx_s, const int* __restrict__ idx_d,
    int K, u32* __restrict__ gcur, u32* __restrict__ binned)
{
    __shared__ u32 hist[NBINS];
    __shared__ u32 base[NBINS];
    int tid = threadIdx.x;
    for (int b = tid; b < NBINS; b += 256) hist[b] = 0;
    __syncthreads();

    int total = 2 * K;
    int e0 = blockIdx.x * EVB;
    int e1 = min(e0 + EVB, total);

    // sweep 1: histogram (reads vox only)
    for (int e = e0 + tid; e < e1; e += 256) {
        int v = (e < K) ? vox_s[e] : vox_d[e - K];
        atomicAdd(&hist[v >> 8], 1u);
    }
    __syncthreads();

    // reserve a contiguous chunk per bin
    for (int b = tid; b < NBINS; b += 256) {
        u32 c = hist[b];
        base[b] = c ? atomicAdd(&gcur[b], c) : 0u;
        hist[b] = 0;  // reuse as local cursor
    }
    __syncthreads();

    // sweep 2: scatter packed (vb<<16 | idx)
    for (int e = e0 + tid; e < e1; e += 256) {
        int v, i;
        if (e < K) { v = vox_s[e];     i = idx_s[e]; }
        else       { v = vox_d[e - K]; i = idx_d[e - K]; }
        int b = v >> 8;
        u32 pos = base[b] + atomicAdd(&hist[b], 1u);
        if (pos < CAP)
            binned[(size_t)b * CAP + pos] = ((u32)(v & 255) << 16) | (u32)i;
    }
}

// One block per bin: accumulate 256-voxel x 32-ch tile in LDS via ds_add_f32,
// then write out[c][v] rows coalesced. Covers every voxel -> no out zero-init.
__global__ __launch_bounds__(512) void accum_k(
    const float* __restrict__ feats_t, const u32* __restrict__ binned,
    const u32* __restrict__ gcur, float* __restrict__ out)
{
    __shared__ float acc[VPB][33];  // +1 pad: conflict-free writeout transpose
    int tid = threadIdx.x;
    int b = blockIdx.x;

    for (int u = tid; u < VPB * 33; u += 512) ((float*)acc)[u] = 0.0f;
    __syncthreads();

    int cnt = (int)min(gcur[b], (u32)CAP);
    const u32* bp = binned + (size_t)b * CAP;
    int slot = tid >> 5;   // 16 event-slots
    int c = tid & 31;

    for (int e = slot; e < cnt; e += 16) {
        u32 p = bp[e];                         // broadcast within 32-lane group
        int vb = (int)(p >> 16);
        int i  = (int)(p & 0xFFFFu);
        float val = feats_t[((size_t)i << 5) + c];  // coalesced 128B gather
        atomicAdd(&acc[vb][c], val);                // ds_add_f32, banks 0..31
    }
    __syncthreads();

    int v0 = b << 8;
    for (int u = tid; u < CCH * VPB; u += 512) {
        int cc = u >> 8;       // 0..31
        int vv = u & 255;      // 0..255
        out[(size_t)cc * NVOX + v0 + vv] = acc[vv][cc];  // coalesced 1KB rows
    }
}

// Fallback: atomics straight into out[c][v].
__global__ __launch_bounds__(256) void scatter_direct_k(
    const float* __restrict__ feats,
    const int* __restrict__ vox_s, const int* __restrict__ vox_d,
    const int* __restrict__ idx_s, const int* __restrict__ idx_d,
    float* __restrict__ out, int K)
{
    int c = threadIdx.x & 31;
    int g = (blockIdx.x * blockDim.x + threadIdx.x) >> 5;
    int gstride = (gridDim.x * blockDim.x) >> 5;
    int total = 2 * K;
    for (int e = g; e < total; e += gstride) {
        int v, i;
        if (e < K) { v = vox_s[e];     i = idx_s[e]; }
        else       { v = vox_d[e - K]; i = idx_d[e - K]; }
        atomicAdd(&out[(size_t)c * NVOX + v], feats[(size_t)c * NPIX + i]);
    }
}

extern "C" void kernel_launch(void* const* d_in, const int* in_sizes, int n_in,
                              void* d_out, int out_size, void* d_ws, size_t ws_size,
                              hipStream_t stream)
{
    const float* feats = (const float*)d_in[0];
    const int* vox_s   = (const int*)d_in[1];
    const int* vox_d   = (const int*)d_in[2];
    const int* idx_s   = (const int*)d_in[3];
    const int* idx_d   = (const int*)d_in[4];
    const int  K       = in_sizes[1];
    float* out = (float*)d_out;

    const size_t binned_bytes = (size_t)NBINS * CAP * sizeof(u32);  // 80 MiB
    const size_t gcur_off     = binned_bytes;
    const size_t gcur_bytes   = (size_t)NBINS * sizeof(u32);        // 16 KiB
    const size_t feats_off    = (gcur_off + gcur_bytes + 255) & ~(size_t)255;
    const size_t need         = feats_off + (size_t)CCH * NPIX * sizeof(float);

    if (ws_size >= need) {
        u32* binned    = (u32*)d_ws;
        u32* gcur      = (u32*)((char*)d_ws + gcur_off);
        float* feats_t = (float*)((char*)d_ws + feats_off);

        hipMemsetAsync(gcur, 0, gcur_bytes, stream);
        transpose_feats_k<<<(CCH * NPIX) / 256, 256, 0, stream>>>(feats, feats_t);
        int nblk = (2 * K + EVB - 1) / EVB;
        scatter_bin_k<<<nblk, 256, 0, stream>>>(vox_s, vox_d, idx_s, idx_d, K, gcur, binned);
        accum_k<<<NBINS, 512, 0, stream>>>(feats_t, binned, gcur, out);
    } else {
        hipMemsetAsync(d_out, 0, (size_t)out_size * sizeof(float), stream);
        scatter_direct_k<<<8192, 256, 0, stream>>>(feats, vox_s, vox_d, idx_s, idx_d, out, K);
    }
}

// Round 3
// 1907.114 us; speedup vs baseline: 1.5562x; 1.5562x over previous
//
#include <hip/hip_runtime.h>

#define CCH 32
#define NPIX 65536
#define NVOX (128 * 128 * 64)   // 2^20
#define CHUNK 1024
#define NCH (NVOX / CHUNK)      // 1024

typedef unsigned int u32;

// feats[c][i] (C x N_PIX) -> feats_t[i][c] (N_PIX x C), 8 MB
__global__ __launch_bounds__(256) void transpose_feats_k(
    const float* __restrict__ feats, float* __restrict__ feats_t)
{
    int gid = blockIdx.x * 256 + threadIdx.x;
    feats_t[gid] = feats[(size_t)(gid & 31) * NPIX + (gid >> 5)];
}

// Pass 1: per-voxel event counts (native int atomics, hist is L2-resident 4MB)
__global__ __launch_bounds__(256) void hist_k(
    const int* __restrict__ vs, const int* __restrict__ vd, int K,
    u32* __restrict__ hist)
{
    int n4 = K >> 2;
    int gs = gridDim.x * blockDim.x;
    int t0 = blockIdx.x * blockDim.x + threadIdx.x;
    const int4* v4s = (const int4*)vs;
    const int4* v4d = (const int4*)vd;
    for (int q = t0; q < n4; q += gs) {
        int4 a = v4s[q];
        atomicAdd(&hist[a.x], 1u); atomicAdd(&hist[a.y], 1u);
        atomicAdd(&hist[a.z], 1u); atomicAdd(&hist[a.w], 1u);
        int4 b = v4d[q];
        atomicAdd(&hist[b.x], 1u); atomicAdd(&hist[b.y], 1u);
        atomicAdd(&hist[b.z], 1u); atomicAdd(&hist[b.w], 1u);
    }
    for (int e = (n4 << 2) + t0; e < K; e += gs) {
        atomicAdd(&hist[vs[e]], 1u);
        atomicAdd(&hist[vd[e]], 1u);
    }
}

// Pass 2a: per-1024-chunk exclusive scan; chunk totals to sums[]
__global__ __launch_bounds__(256) void scan1_k(
    const u32* __restrict__ hist, u32* __restrict__ off, u32* __restrict__ sums)
{
    __shared__ u32 tmp[256];
    int t = threadIdx.x;
    size_t base = (size_t)blockIdx.x * CHUNK + t * 4;
    uint4 h = *(const uint4*)&hist[base];
    u32 s = h.x + h.y + h.z + h.w;
    tmp[t] = s;
    __syncthreads();
    for (int d = 1; d < 256; d <<= 1) {
        u32 x = (t >= d) ? tmp[t - d] : 0u;
        __syncthreads();
        tmp[t] += x;
        __syncthreads();
    }
    u32 excl = tmp[t] - s;
    uint4 o;
    o.x = excl; o.y = excl + h.x; o.z = o.y + h.y; o.w = o.z + h.z;
    *(uint4*)&off[base] = o;
    if (t == 255) sums[blockIdx.x] = tmp[255];
}

// Pass 2b: exclusive scan of the 1024 chunk totals, in place (one block)
__global__ __launch_bounds__(256) void scan2_k(u32* __restrict__ sums)
{
    __shared__ u32 tmp[256];
    int t = threadIdx.x;
    uint4 h = *(uint4*)&sums[t * 4];
    u32 s = h.x + h.y + h.z + h.w;
    tmp[t] = s;
    __syncthreads();
    for (int d = 1; d < 256; d <<= 1) {
        u32 x = (t >= d) ? tmp[t - d] : 0u;
        __syncthreads();
        tmp[t] += x;
        __syncthreads();
    }
    u32 excl = tmp[t] - s;
    uint4 o;
    o.x = excl; o.y = excl + h.x; o.z = o.y + h.y; o.w = o.z + h.z;
    *(uint4*)&sums[t * 4] = o;
}

// Pass 2c: add chunk bases -> off[] is the global exclusive scan
__global__ __launch_bounds__(256) void scan3_k(
    u32* __restrict__ off, const u32* __restrict__ sums)
{
    int gid = blockIdx.x * 256 + threadIdx.x;   // over NVOX/4
    u32 add = sums[(gid * 4) >> 10];
    uint4* o4 = (uint4*)off;
    uint4 o = o4[gid];
    o.x += add; o.y += add; o.z += add; o.w += add;
    o4[gid] = o;
}

// Pass 3: scatter pixel-idx into per-voxel contiguous runs.
// Afterwards off[v] = inclusive boundary (end of run v) -- reused by accum.
__global__ __launch_bounds__(256) void scatter_evt_k(
    const int* __restrict__ vs, const int* __restrict__ vd,
    const int* __restrict__ is_, const int* __restrict__ id_,
    int K, u32* __restrict__ off, u32* __restrict__ evt)
{
    int n4 = K >> 2;
    int gs = gridDim.x * blockDim.x;
    int t0 = blockIdx.x * blockDim.x + threadIdx.x;
    {
        const int4* v4 = (const int4*)vs;
        const int4* i4 = (const int4*)is_;
        for (int q = t0; q < n4; q += gs) {
            int4 v = v4[q]; int4 i = i4[q];
            evt[atomicAdd(&off[v.x], 1u)] = (u32)i.x;
            evt[atomicAdd(&off[v.y], 1u)] = (u32)i.y;
            evt[atomicAdd(&off[v.z], 1u)] = (u32)i.z;
            evt[atomicAdd(&off[v.w], 1u)] = (u32)i.w;
        }
    }
    {
        const int4* v4 = (const int4*)vd;
        const int4* i4 = (const int4*)id_;
        for (int q = t0; q < n4; q += gs) {
            int4 v = v4[q]; int4 i = i4[q];
            evt[atomicAdd(&off[v.x], 1u)] = (u32)i.x;
            evt[atomicAdd(&off[v.y], 1u)] = (u32)i.y;
            evt[atomicAdd(&off[v.z], 1u)] = (u32)i.z;
            evt[atomicAdd(&off[v.w], 1u)] = (u32)i.w;
        }
    }
    for (int e = (n4 << 2) + t0; e < K; e += gs) {
        evt[atomicAdd(&off[vs[e]], 1u)] = (u32)is_[e];
        evt[atomicAdd(&off[vd[e]], 1u)] = (u32)id_[e];
    }
}

// Pass 4: segmented register reduction. 32-lane group owns 8 consecutive
// voxels = one contiguous event range. Lane = channel. No atomics anywhere.
__global__ __launch_bounds__(256) void accum_k(
    const float* __restrict__ feats_t, const u32* __restrict__ evt,
    const u32* __restrict__ off, u32 total, float* __restrict__ out)
{
    __shared__ float tile[64][33];
    int tid = threadIdx.x;
    int g = tid >> 5, c = tid & 31;
    int v0 = blockIdx.x << 6;
    int firstv = v0 + (g << 3);

    int ai = firstv - 1 + c;
    u32 o = (c < 9 && ai >= 0) ? off[ai] : 0u;   // lane 0: start, lanes 1..8: ends of voxels 0..7
    u32 start8 = __shfl(o, 0, 32);
    u32 end8   = __shfl(o, 8, 32);

    int lv = 0;
    u32 vend = __shfl(o, 1, 32);
    float a = 0.f;

    for (u32 s = start8; s < end8; s += 32) {
        int rem = (int)min(32u, end8 - s);
        u32 ev = evt[min(s + (u32)c, total - 1)];   // coalesced 128B: 32 events
#pragma unroll
        for (int j = 0; j < 32; ++j) {
            if (j < rem) {
                while (s + (u32)j >= vend && lv < 8) {   // voxel boundary: flush
                    tile[(g << 3) + lv][c] = a;
                    a = 0.f;
                    ++lv;
                    vend = __shfl(o, lv + 1, 32);
                }
                u32 idx = __shfl(ev, j, 32);
                a += feats_t[((size_t)idx << 5) + c];    // coalesced 128B gather
            }
        }
    }
    while (lv < 8) { tile[(g << 3) + lv][c] = a; a = 0.f; ++lv; }
    __syncthreads();

    for (int u = tid; u < CCH * 64; u += 256) {
        int cc = u >> 6, vv = u & 63;
        out[((size_t)cc << 20) + v0 + vv] = tile[vv][cc];   // coalesced 256B rows
    }
}

// Fallback: atomics straight into out[c][v].
__global__ __launch_bounds__(256) void scatter_direct_k(
    const float* __restrict__ feats,
    const int* __restrict__ vox_s, const int* __restrict__ vox_d,
    const int* __restrict__ idx_s, const int* __restrict__ idx_d,
    float* __restrict__ out, int K)
{
    int c = threadIdx.x & 31;
    int g = (blockIdx.x * blockDim.x + threadIdx.x) >> 5;
    int gstride = (gridDim.x * blockDim.x) >> 5;
    int total = 2 * K;
    for (int e = g; e < total; e += gstride) {
        int v, i;
        if (e < K) { v = vox_s[e];     i = idx_s[e]; }
        else       { v = vox_d[e - K]; i = idx_d[e - K]; }
        atomicAdd(&out[(size_t)c * NVOX + v], feats[(size_t)c * NPIX + i]);
    }
}

extern "C" void kernel_launch(void* const* d_in, const int* in_sizes, int n_in,
                              void* d_out, int out_size, void* d_ws, size_t ws_size,
                              hipStream_t stream)
{
    const float* feats = (const float*)d_in[0];
    const int* vox_s   = (const int*)d_in[1];
    const int* vox_d   = (const int*)d_in[2];
    const int* idx_s   = (const int*)d_in[3];
    const int* idx_d   = (const int*)d_in[4];
    const int  K       = in_sizes[1];
    float* out = (float*)d_out;
    const u32 total = (u32)(2 * K);

    const size_t evt_bytes   = (size_t)total * sizeof(u32);          // 64 MB
    const size_t feats_off   = (evt_bytes + 255) & ~(size_t)255;
    const size_t hist_off    = feats_off + (size_t)CCH * NPIX * 4;   // +8 MB
    const size_t off_off     = hist_off + (size_t)NVOX * 4;          // +4 MB
    const size_t sums_off    = off_off + (size_t)NVOX * 4;           // +4 MB
    const size_t need        = sums_off + (size_t)NCH * 4;

    if (ws_size >= need) {
        u32*   evt     = (u32*)d_ws;
        float* feats_t = (float*)((char*)d_ws + feats_off);
        u32*   hist    = (u32*)((char*)d_ws + hist_off);
        u32*   off     = (u32*)((char*)d_ws + off_off);
        u32*   sums    = (u32*)((char*)d_ws + sums_off);

        hipMemsetAsync(hist, 0, (size_t)NVOX * 4, stream);
        transpose_feats_k<<<(CCH * NPIX) / 256, 256, 0, stream>>>(feats, feats_t);
        hist_k<<<2048, 256, 0, stream>>>(vox_s, vox_d, K, hist);
        scan1_k<<<NCH, 256, 0, stream>>>(hist, off, sums);
        scan2_k<<<1, 256, 0, stream>>>(sums);
        scan3_k<<<NVOX / 4 / 256, 256, 0, stream>>>(off, sums);
        scatter_evt_k<<<2048, 256, 0, stream>>>(vox_s, vox_d, idx_s, idx_d, K, off, evt);
        accum_k<<<NVOX / 64, 256, 0, stream>>>(feats_t, evt, off, total, out);
    } else {
        hipMemsetAsync(d_out, 0, (size_t)out_size * sizeof(float), stream);
        scatter_direct_k<<<8192, 256, 0, stream>>>(feats, vox_s, vox_d, idx_s, idx_d, out, K);
    }
}

// Round 4
// 656.957 us; speedup vs baseline: 4.5175x; 2.9030x over previous
//
#include <hip/hip_runtime.h>

#define CCH 32
#define NPIX 65536
#define NVOX (128 * 128 * 64)   // 2^20
#define NBINS 4096
#define VPB 256                 // voxels per bin (v & 255)
#define CAP 5120                // slots per bin; Poisson mean 3906, sigma 62
#define EVB 32768               // events per block in the binning pass

typedef unsigned int u32;

// feats[c][i] (C x N_PIX) -> feats_t[i][c] (N_PIX x C), 8 MB
__global__ __launch_bounds__(256) void transpose_feats_k(
    const float* __restrict__ feats, float* __restrict__ feats_t)
{
    int gid = blockIdx.x * 256 + threadIdx.x;
    feats_t[gid] = feats[(size_t)(gid & 31) * NPIX + (gid >> 5)];
}

// Bin events into 4096 voxel bins. LDS histogram (native int ds_add) ->
// one chunk-reserving global atomic per nonzero bin -> packed scatter.
__global__ __launch_bounds__(512) void scatter_bin_k(
    const int* __restrict__ vox_s, const int* __restrict__ vox_d,
    const int* __restrict__ idx_s, const int* __restrict__ idx_d,
    int K, u32* __restrict__ gcur, u32* __restrict__ binned)
{
    __shared__ u32 hist[NBINS];
    __shared__ u32 base[NBINS];
    int tid = threadIdx.x;
    for (int b = tid; b < NBINS; b += 512) hist[b] = 0;
    __syncthreads();

    int total = 2 * K;
    int e0 = blockIdx.x * EVB;
    int e1 = min(e0 + EVB, total);

    for (int e = e0 + tid; e < e1; e += 512) {
        int v = (e < K) ? vox_s[e] : vox_d[e - K];
        atomicAdd(&hist[v >> 8], 1u);
    }
    __syncthreads();

    for (int b = tid; b < NBINS; b += 512) {
        u32 c = hist[b];
        base[b] = c ? atomicAdd(&gcur[b], c) : 0u;
        hist[b] = 0;  // reuse as local cursor
    }
    __syncthreads();

    for (int e = e0 + tid; e < e1; e += 512) {
        int v, i;
        if (e < K) { v = vox_s[e];     i = idx_s[e]; }
        else       { v = vox_d[e - K]; i = idx_d[e - K]; }
        int b = v >> 8;
        u32 pos = base[b] + atomicAdd(&hist[b], 1u);
        if (pos < CAP)
            binned[(size_t)b * CAP + pos] = ((u32)(v & 255) << 16) | (u32)i;
    }
}

// One block (1024 thr = 16 waves) per bin: counting-sort the bin's events in
// LDS (native int atomics only), then register-accumulate. Wave w owns voxels
// w*16..w*16+15; lane = (slot 0..3) x (channel-pair 0..15). Per voxel: 4
// independent float2 accumulation chains, shfl_xor reduce, plain LDS write.
__global__ __launch_bounds__(1024) void accum_k(
    const float* __restrict__ feats_t, const u32* __restrict__ binned,
    const u32* __restrict__ gcur, float* __restrict__ out)
{
    __shared__ u32 sorted[CAP];        // 20 KB
    __shared__ float tile[VPB][33];    // 33.8 KB
    __shared__ u32 hist[VPB];
    __shared__ u32 cursor[VPB];
    __shared__ u32 voff[VPB + 1];
    __shared__ u32 sc[VPB];

    int t = threadIdx.x;
    int b = blockIdx.x;
    int cnt = (int)min(gcur[b], (u32)CAP);
    const u32* bp = binned + (size_t)b * CAP;

    if (t < VPB) hist[t] = 0;
    __syncthreads();

    // sweep 1: histogram over 256 within-bin voxels (native ds_add)
    for (int e = t; e < cnt; e += 1024)
        atomicAdd(&hist[bp[e] >> 16], 1u);
    __syncthreads();

    // exclusive scan of 256 counters (Hillis-Steele; all threads hit barriers)
    if (t < VPB) sc[t] = hist[t];
    __syncthreads();
    for (int d = 1; d < VPB; d <<= 1) {
        u32 x = 0;
        if (t < VPB && t >= d) x = sc[t - d];
        __syncthreads();
        if (t < VPB) sc[t] += x;
        __syncthreads();
    }
    if (t < VPB) {
        u32 excl = sc[t] - hist[t];
        voff[t] = excl;
        cursor[t] = excl;
    }
    if (t == 0) voff[VPB] = (u32)cnt;
    __syncthreads();

    // sweep 2: scatter pixel-idx into per-voxel runs (LDS cursor, native)
    for (int e = t; e < cnt; e += 1024) {
        u32 p = bp[e];
        u32 pos = atomicAdd(&cursor[p >> 16], 1u);
        sorted[pos] = p & 0xFFFFu;
    }
    __syncthreads();

    // register accumulation
    const float2* f2 = (const float2*)feats_t;
    int wave = t >> 6;          // 0..15
    int lane = t & 63;
    int chp  = lane & 15;       // channels 2chp, 2chp+1
    int slot = lane >> 4;       // 0..3

    for (int j = 0; j < 16; ++j) {
        int vb = (wave << 4) + j;
        int s  = (int)voff[vb];
        int e2 = (int)voff[vb + 1];
        float ax = 0.f, ay = 0.f;
        int k = s + slot;
        bool valid = (k < e2);
        int idx = valid ? (int)sorted[k] : 0;
        while (valid) {
            float2 v = f2[((size_t)idx << 4) + chp];  // 512B/wave, 4 events
            int kn = k + 4;
            bool vn = kn < e2;
            int idxn = vn ? (int)sorted[kn] : 0;      // prefetch next idx
            ax += v.x; ay += v.y;
            k = kn; idx = idxn; valid = vn;
        }
        ax += __shfl_xor(ax, 16); ay += __shfl_xor(ay, 16);
        ax += __shfl_xor(ax, 32); ay += __shfl_xor(ay, 32);
        if (slot == 0) {
            tile[vb][2 * chp]     = ax;
            tile[vb][2 * chp + 1] = ay;
        }
    }
    __syncthreads();

    // coalesced transposed writeout: out[c][v0..v0+255]
    int v0 = b << 8;
    for (int u = t; u < CCH * VPB; u += 1024) {
        int cc = u >> 8, vv = u & 255;
        out[((size_t)cc << 20) + v0 + vv] = tile[vv][cc];
    }
}

// Fallback: atomics straight into out[c][v].
__global__ __launch_bounds__(256) void scatter_direct_k(
    const float* __restrict__ feats,
    const int* __restrict__ vox_s, const int* __restrict__ vox_d,
    const int* __restrict__ idx_s, const int* __restrict__ idx_d,
    float* __restrict__ out, int K)
{
    int c = threadIdx.x & 31;
    int g = (blockIdx.x * blockDim.x + threadIdx.x) >> 5;
    int gstride = (gridDim.x * blockDim.x) >> 5;
    int total = 2 * K;
    for (int e = g; e < total; e += gstride) {
        int v, i;
        if (e < K) { v = vox_s[e];     i = idx_s[e]; }
        else       { v = vox_d[e - K]; i = idx_d[e - K]; }
        atomicAdd(&out[(size_t)c * NVOX + v], feats[(size_t)c * NPIX + i]);
    }
}

extern "C" void kernel_launch(void* const* d_in, const int* in_sizes, int n_in,
                              void* d_out, int out_size, void* d_ws, size_t ws_size,
                              hipStream_t stream)
{
    const float* feats = (const float*)d_in[0];
    const int* vox_s   = (const int*)d_in[1];
    const int* vox_d   = (const int*)d_in[2];
    const int* idx_s   = (const int*)d_in[3];
    const int* idx_d   = (const int*)d_in[4];
    const int  K       = in_sizes[1];
    float* out = (float*)d_out;

    const size_t binned_bytes = (size_t)NBINS * CAP * sizeof(u32);  // 80 MiB
    const size_t gcur_off     = binned_bytes;
    const size_t gcur_bytes   = (size_t)NBINS * sizeof(u32);
    const size_t feats_off    = (gcur_off + gcur_bytes + 255) & ~(size_t)255;
    const size_t need         = feats_off + (size_t)CCH * NPIX * sizeof(float);

    if (ws_size >= need) {
        u32* binned    = (u32*)d_ws;
        u32* gcur      = (u32*)((char*)d_ws + gcur_off);
        float* feats_t = (float*)((char*)d_ws + feats_off);

        hipMemsetAsync(gcur, 0, gcur_bytes, stream);
        transpose_feats_k<<<(CCH * NPIX) / 256, 256, 0, stream>>>(feats, feats_t);
        int nblk = (2 * K + EVB - 1) / EVB;
        scatter_bin_k<<<nblk, 512, 0, stream>>>(vox_s, vox_d, idx_s, idx_d, K, gcur, binned);
        accum_k<<<NBINS, 1024, 0, stream>>>(feats_t, binned, gcur, out);
    } else {
        hipMemsetAsync(d_out, 0, (size_t)out_size * sizeof(float), stream);
        scatter_direct_k<<<8192, 256, 0, stream>>>(feats, vox_s, vox_d, idx_s, idx_d, out, K);
    }
}